// Round 10
// baseline (470.590 us; speedup 1.0000x reference)
//
#include <hip/hip_runtime.h>
#include <stdint.h>

#define HF_ 160
#define WF_ 160
#define HFW 25600          // 160*160
#define A_N 15
#define NTOT 384000        // 15*160*160
#define PRE_N 3000
#define KEEP_N 300
#define FEAT_N 490
#define HID_N 2048
#define RC_N 900
#define FIN_N 100
#define TIE_CAP 1024
#define NW 47              // ceil(3000/64) uint64 words per rpn mask row
#define NSTAGE 320         // rows of rpn rowmask staged in LDS by k_rpn_scan
#define RNW 15             // ceil(900/64) uint64 words per rcnn mask row
#define FC1_MT 10          // rows per fc1 block
#define FC1_KP 496         // K padded to multiple of 16 (16B-aligned float4 rows)
#define ZN (65536 * 2 + 32) // hist1+hist2+meta words to zero

// Anchor half-extents, float64-derived literals (r in {0.5,1,2} x s in {2,4,8,16,32})
__constant__ float c_hw[15] = {
  22.627416997969522f, 45.254833995939045f, 90.509667991878090f, 181.01933598375618f, 362.03867196751236f,
  16.0f, 32.0f, 64.0f, 128.0f, 256.0f,
  11.313708498984761f, 22.627416997969522f, 45.254833995939045f, 90.509667991878090f, 181.01933598375618f
};
__constant__ float c_hh[15] = {
  11.313708498984761f, 22.627416997969522f, 45.254833995939045f, 90.509667991878090f, 181.01933598375618f,
  16.0f, 32.0f, 64.0f, 128.0f, 256.0f,
  22.627416997969522f, 45.254833995939045f, 90.509667991878090f, 181.01933598375618f, 362.03867196751236f
};

__device__ __forceinline__ void decode_one(
    float ax1, float ay1, float ax2, float ay2,
    float dx, float dy, float dw, float dh,
    float& ox1, float& oy1, float& ox2, float& oy2)
{
#pragma clang fp contract(off)
  float wa = (ax2 - ax1) + 1.0f;
  float ha = (ay2 - ay1) + 1.0f;
  float cxa = ax1 + 0.5f * wa;
  float cya = ay1 + 0.5f * ha;
  float d0 = dx * 0.1f;
  float d1 = dy * 0.1f;
  float d2 = dw * 0.2f;
  float d3 = dh * 0.2f;
  float cx = d0 * wa + cxa;
  float cy = d1 * ha + cya;
  float w  = wa * expf(fminf(d2, 4.0f));
  float h  = ha * expf(fminf(d3, 4.0f));
  float x1 = cx - 0.5f * w;
  float y1 = cy - 0.5f * h;
  float x2 = cx + 0.5f * w;
  float y2 = cy + 0.5f * h;
  ox1 = fminf(fmaxf(x1, 0.0f), 2559.0f);
  oy1 = fminf(fmaxf(y1, 0.0f), 2559.0f);
  ox2 = fminf(fmaxf(x2, 0.0f), 2559.0f);
  oy2 = fminf(fmaxf(y2, 0.0f), 2559.0f);
}

__device__ __forceinline__ float iou_ref(
    float ax1, float ay1, float ax2, float ay2, float areaA,
    float bx1, float by1, float bx2, float by2)
{
#pragma clang fp contract(off)
  float ix1 = fmaxf(ax1, bx1);
  float iy1 = fmaxf(ay1, by1);
  float ix2 = fminf(ax2, bx2);
  float iy2 = fminf(ay2, by2);
  float iw = fmaxf((ix2 - ix1) + 1.0f, 0.0f);
  float ih = fmaxf((iy2 - iy1) + 1.0f, 0.0f);
  float inter = iw * ih;
  float areaB = fmaxf((bx2 - bx1) + 1.0f, 0.0f) * fmaxf((by2 - by1) + 1.0f, 0.0f);
  float den = fmaxf(areaA + areaB - inter, 1e-6f);
  return inter / den;
}

// Decode all anchors, apply (w>=8, h>=8, score>0.2) filter; write filtered
// scores. Also zeroes hist1/hist2/meta (fused former k_zero).
__global__ void k_decode_score(const float* __restrict__ cls,
                               const float* __restrict__ bbox,
                               float* __restrict__ scores,
                               uint32_t* __restrict__ histzero)
{
  int e = blockIdx.x * 256 + threadIdx.x;
  if (e < ZN) histzero[e] = 0u;
  if (e >= NTOT) return;
  int a   = e / HFW;
  int rem = e - a * HFW;
  int i   = rem / WF_;
  int j   = rem - i * WF_;
  float score = cls[(A_N + a) * HFW + rem];
  float gx = (float)(j * 16);
  float gy = (float)(i * 16);
  float hw = c_hw[a], hh = c_hh[a];
  float dx = bbox[(a * 4 + 0) * HFW + rem];
  float dy = bbox[(a * 4 + 1) * HFW + rem];
  float dw = bbox[(a * 4 + 2) * HFW + rem];
  float dh = bbox[(a * 4 + 3) * HFW + rem];
  float x1, y1, x2, y2;
  decode_one(gx - hw, gy - hh, gx + hw, gy + hh, dx, dy, dw, dh, x1, y1, x2, y2);
  float bw, bh;
  {
#pragma clang fp contract(off)
    bw = (x2 - x1) + 1.0f;
    bh = (y2 - y1) + 1.0f;
  }
  bool ok = (bw >= 8.0f) && (bh >= 8.0f) && (score > 0.2f);
  scores[e] = ok ? score : 0.0f;
}

// Histogram of high-16 float bits (positive scores); LDS window covers [0.125,2).
__global__ void k_hist_hi(const float* __restrict__ scores, uint32_t* __restrict__ hist)
{
  __shared__ uint32_t lh[512];
  int t = threadIdx.x;
  for (int i = t; i < 512; i += 256) lh[i] = 0u;
  __syncthreads();
  int e = blockIdx.x * 256 + t;
  if (e < NTOT) {
    float s = scores[e];
    if (s > 0.0f) {
      uint32_t b = __float_as_uint(s) >> 16;
      if (b >= 0x3E00u && b < 0x4000u) atomicAdd(&lh[b - 0x3E00u], 1u);
      else atomicAdd(&hist[b], 1u);
    }
  }
  __syncthreads();
  for (int i = t; i < 512; i += 256) {
    uint32_t v = lh[i];
    if (v) atomicAdd(&hist[0x3E00u + i], v);
  }
}

// Parallel selection of the hi-16 threshold bin.
// meta: [0]=B1 [1]=K_rem [2]=nocross [3]=T
__global__ void __launch_bounds__(1024) k_findbin1(const uint32_t* __restrict__ hist,
                                                   uint32_t* __restrict__ meta)
{
  __shared__ uint32_t sfx[1024];
  __shared__ int s_chunk;
  __shared__ uint32_t s_exc;
  int t = threadIdx.x;
  if (t == 0) s_chunk = -1;
  const uint32_t* hp = hist + t * 64;
  uint32_t s = 0;
#pragma unroll
  for (int b = 0; b < 64; b++) s += hp[b];
  sfx[t] = s;
  __syncthreads();
  for (int d = 1; d < 1024; d <<= 1) {
    uint32_t v = (t + d < 1024) ? sfx[t + d] : 0u;
    __syncthreads();
    sfx[t] += v;
    __syncthreads();
  }
  uint32_t inc = sfx[t];
  uint32_t exc = (t < 1023) ? sfx[t + 1] : 0u;
  if (exc < (uint32_t)PRE_N && inc >= (uint32_t)PRE_N) { s_chunk = t; s_exc = exc; }
  __syncthreads();
  int c = s_chunk;
  if (c < 0) {
    if (t == 0) { meta[0] = 0u; meta[1] = 0u; meta[2] = 1u; }
    return;
  }
  if (t < 64) {
    uint32_t h = hist[c * 64 + t];
    uint32_t v = h;
#pragma unroll
    for (int d = 1; d < 64; d <<= 1) {
      uint32_t o = (uint32_t)__shfl_down((int)v, d);
      v += (t + d < 64) ? o : 0u;
    }
    uint32_t before = s_exc + (v - h);   // keys strictly above bin (c*64+t)
    if (before < (uint32_t)PRE_N && before + h >= (uint32_t)PRE_N) {
      meta[0] = (uint32_t)(c * 64 + t);
      meta[1] = (uint32_t)PRE_N - before;
      meta[2] = 0u;
    }
  }
}

__global__ void k_hist_lo(const float* __restrict__ scores,
                          const uint32_t* __restrict__ meta,
                          uint32_t* __restrict__ hist2)
{
  if (meta[2]) return;
  uint32_t B1 = meta[0];
  int e = blockIdx.x * 256 + threadIdx.x;
  if (e >= NTOT) return;
  float s = scores[e];
  if (s <= 0.0f) return;
  uint32_t bits = __float_as_uint(s);
  if ((bits >> 16) == B1) atomicAdd(&hist2[bits & 0xFFFFu], 1u);
}

// Parallel selection of the lo-16 threshold within bin B1.
__global__ void __launch_bounds__(1024) k_findT(const uint32_t* __restrict__ hist2,
                                                uint32_t* __restrict__ meta)
{
  if (meta[2]) { if (threadIdx.x == 0) meta[3] = 0u; return; }
  __shared__ uint32_t sfx[1024];
  __shared__ int s_chunk;
  __shared__ uint32_t s_exc;
  int t = threadIdx.x;
  if (t == 0) s_chunk = -1;
  uint32_t K = meta[1];
  const uint32_t* hp = hist2 + t * 64;
  uint32_t s = 0;
#pragma unroll
  for (int b = 0; b < 64; b++) s += hp[b];
  sfx[t] = s;
  __syncthreads();
  for (int d = 1; d < 1024; d <<= 1) {
    uint32_t v = (t + d < 1024) ? sfx[t + d] : 0u;
    __syncthreads();
    sfx[t] += v;
    __syncthreads();
  }
  uint32_t inc = sfx[t];
  uint32_t exc = (t < 1023) ? sfx[t + 1] : 0u;
  if (exc < K && inc >= K) { s_chunk = t; s_exc = exc; }
  __syncthreads();
  int c = s_chunk;
  if (c < 0) { if (t == 0) meta[3] = 0u; return; }   // should not happen
  if (t < 64) {
    uint32_t h = hist2[c * 64 + t];
    uint32_t v = h;
#pragma unroll
    for (int d = 1; d < 64; d <<= 1) {
      uint32_t o = (uint32_t)__shfl_down((int)v, d);
      v += (t + d < 64) ? o : 0u;
    }
    uint32_t before = s_exc + (v - h);
    if (before < K && before + h >= K)
      meta[3] = (meta[0] << 16) | (uint32_t)(c * 64 + t);
  }
}

// key = scoreBits<<32 | ~idx  → descending order == (score desc, idx asc) == jax top_k order
__global__ void k_compact(const float* __restrict__ scores,
                          const uint32_t* __restrict__ meta,
                          uint64_t* __restrict__ gt,
                          uint64_t* __restrict__ tie,
                          uint32_t* __restrict__ cnts)
{
  int e = blockIdx.x * 256 + threadIdx.x;
  if (e >= NTOT) return;
  float s = scores[e];
  if (s <= 0.0f) return;
  uint32_t bits = __float_as_uint(s);
  uint32_t T = meta[3];
  uint64_t key = ((uint64_t)bits << 32) | (uint32_t)(~(uint32_t)e);
  if (bits > T) {
    uint32_t p = atomicAdd(&cnts[0], 1u);
    if (p < (uint32_t)PRE_N) gt[p] = key;
  } else if (bits == T) {
    uint32_t p = atomicAdd(&cnts[1], 1u);
    if (p < (uint32_t)TIE_CAP) tie[p] = key;
  }
}

// Rank-based sort+gather: position of key k in descending order == #{keys > k}.
// Keys unique (idx embedded) → exact permutation, no sort network, no barriers
// after staging. Each thread ranks its key then decodes its box to slot r.
// Slots r >= M stay unwritten (poison) — provably never read (scan bounds Mp).
__global__ void __launch_bounds__(256) k_rank_gather(
    const uint64_t* __restrict__ gt,
    const uint64_t* __restrict__ tie,
    const uint32_t* __restrict__ cnts,
    const float* __restrict__ bbox,
    float* __restrict__ bxx1, float* __restrict__ bxy1,
    float* __restrict__ bxx2, float* __restrict__ bxy2)
{
  __shared__ uint64_t keys[4096];   // 32 KB
  int t = threadIdx.x;
  uint32_t ngt = min(cnts[0], (uint32_t)PRE_N);
  uint32_t nte = min(cnts[1], (uint32_t)TIE_CAP);
  uint32_t M = ngt + nte;           // <= 4023
  for (int s = t; s < 4096; s += 256) {
    uint64_t k = 0;
    if ((uint32_t)s < ngt) k = gt[s];
    else if ((uint32_t)s < M) k = tie[s - ngt];
    keys[s] = k;
  }
  __syncthreads();
  int e = blockIdx.x * 256 + t;
  uint64_t my = keys[e];
  if (my == 0) return;
  int r = 0;
#pragma unroll 4
  for (int j = 0; j < 4096; j += 4) {
    uint64_t k0 = keys[j + 0];      // uniform address → LDS broadcast
    uint64_t k1 = keys[j + 1];
    uint64_t k2 = keys[j + 2];
    uint64_t k3 = keys[j + 3];
    r += (k0 > my) ? 1 : 0;
    r += (k1 > my) ? 1 : 0;
    r += (k2 > my) ? 1 : 0;
    r += (k3 > my) ? 1 : 0;
  }
  if (r >= PRE_N) return;
  int idx = (int)(~(uint32_t)(my & 0xFFFFFFFFull));
  int a   = idx / HFW;
  int rem = idx - a * HFW;
  int i   = rem / WF_;
  int j   = rem - i * WF_;
  float gx = (float)(j * 16);
  float gy = (float)(i * 16);
  float hw = c_hw[a], hh = c_hh[a];
  float dx = bbox[(a * 4 + 0) * HFW + rem];
  float dy = bbox[(a * 4 + 1) * HFW + rem];
  float dw = bbox[(a * 4 + 2) * HFW + rem];
  float dh = bbox[(a * 4 + 3) * HFW + rem];
  float x1, y1, x2, y2;
  decode_one(gx - hw, gy - hh, gx + hw, gy + hh, dx, dy, dw, dh, x1, y1, x2, y2);
  bxx1[r] = x1; bxy1[r] = y1; bxx2[r] = x2; bxy2[r] = y2;
}

// Parallel IoU mask (upper triangle only — rows only suppress later candidates).
// Also emits diag[row] = word (row>>6) of row (the scan's critical-path word).
__global__ void __launch_bounds__(256) k_iou_mask(
    const float* __restrict__ bxx1, const float* __restrict__ bxy1,
    const float* __restrict__ bxx2, const float* __restrict__ bxy2,
    uint64_t* __restrict__ rowmask, uint64_t* __restrict__ diag)
{
  __shared__ float s1[PRE_N], s2[PRE_N], s3[PRE_N], s4[PRE_N];  // 48 KB
  int t = threadIdx.x;
  for (int e = t; e < PRE_N; e += 256) {
    s1[e] = bxx1[e]; s2[e] = bxy1[e]; s3[e] = bxx2[e]; s4[e] = bxy2[e];
  }
  __syncthreads();
  int task = blockIdx.x * 256 + t;
  if (task >= PRE_N * NW) return;
  int row = task / NW;
  int w   = task - row * NW;
  if ((w + 1) * 64 <= row) {       // strictly-lower word: never read meaningfully
    rowmask[(size_t)row * NW + w] = 0;
    return;
  }
  float ax1 = s1[row], ay1 = s2[row], ax2 = s3[row], ay2 = s4[row];
  float areaA;
  {
#pragma clang fp contract(off)
    areaA = fmaxf((ax2 - ax1) + 1.0f, 0.0f) * fmaxf((ay2 - ay1) + 1.0f, 0.0f);
  }
  int j0 = w << 6;
  uint64_t bits = 0;
  for (int off = 0; off < 64; off++) {
    int jj = (off + t) & 63;
    int j = j0 + jj;
    if (j < PRE_N) {
      float iou = iou_ref(ax1, ay1, ax2, ay2, areaA, s1[j], s2[j], s3[j], s4[j]);
      if (iou > 0.7f) bits |= 1ull << jj;
    }
  }
  rowmask[(size_t)row * NW + w] = bits;
  if (w == (row >> 6)) diag[row] = bits;
}

// ctz-enumeration greedy scan: in sorted order every surviving zero bit IS a
// keep. rem updated via the diagonal word (uniform LDS read); full rows feed
// sup via a 1-deep pend defer (off the critical chain until word boundary).
__global__ void __launch_bounds__(256) k_rpn_scan(
    const float* __restrict__ bxx1, const float* __restrict__ bxy1,
    const float* __restrict__ bxx2, const float* __restrict__ bxy2,
    const uint32_t* __restrict__ cnts,
    const uint64_t* __restrict__ rowmask,
    const uint64_t* __restrict__ diag,
    float* __restrict__ rois, uint32_t* __restrict__ valid)
{
  __shared__ uint64_t rowstage[NSTAGE * NW];   // 120320 B
  __shared__ uint64_t sdiag[PRE_N];            // 24000 B
  __shared__ int keepIdx[KEEP_N];
  __shared__ int s_nkeep;
  int t = threadIdx.x;
  for (int e = t; e < NSTAGE * NW; e += 256) rowstage[e] = rowmask[e];
  for (int e = t; e < PRE_N; e += 256) sdiag[e] = diag[e];
  __syncthreads();
  if (t < 64) {
    int lane = t;
    uint32_t Mp = min(cnts[0] + min(cnts[1], (uint32_t)TIE_CAP), (uint32_t)PRE_N);
    uint64_t sup = 0, pend = 0;
    int nk = 0;
    int nwords = (int)((Mp + 63u) >> 6);
    for (int w = 0; w < nwords && nk < KEEP_N; w++) {
      sup |= pend; pend = 0;
      uint64_t cw = (uint64_t)__shfl((unsigned long long)sup, w);
      int lim = (int)Mp - (w << 6);
      uint64_t range = (lim >= 64) ? ~0ull : ((1ull << lim) - 1ull);
      uint64_t rem = (~cw) & range;
      while (rem && nk < KEEP_N) {
        int b = __builtin_ctzll(rem);
        int i = (w << 6) + b;
        if (lane == 0) keepIdx[nk] = i;
        nk++;
        uint64_t roww = sdiag[i];               // uniform LDS broadcast
        uint64_t rowl = 0;
        if (lane < NW)
          rowl = (i < NSTAGE) ? rowstage[i * NW + lane]
                              : rowmask[(size_t)i * NW + lane];
        sup |= pend;
        pend = rowl;
        rem &= ~(roww | (1ull << b));
      }
    }
    sup |= pend;
    if (lane == 0) s_nkeep = nk;
  }
  __syncthreads();
  int nk2 = s_nkeep;
  for (int k = t; k < nk2; k += 256) {
    int i = keepIdx[k];
    rois[k * 4 + 0] = bxx1[i];
    rois[k * 4 + 1] = bxy1[i];
    rois[k * 4 + 2] = bxx2[i];
    rois[k * 4 + 3] = bxy2[i];
    valid[k] = 1u;
  }
  for (int e = nk2 * 4 + t; e < KEEP_N * 4; e += 256) rois[e] = 0.0f;
  for (int e = nk2 + t; e < KEEP_N; e += 256) valid[e] = 0u;
}

__global__ void __launch_bounds__(512) k_psroi(const float* __restrict__ ft,
                                               const float* __restrict__ rois,
                                               const uint32_t* __restrict__ valid,
                                               float* __restrict__ feats)
{
#pragma clang fp contract(off)
  int r = blockIdx.x;
  int t = threadIdx.x;
  if (t >= FEAT_N) return;
  float x1 = rois[r * 4 + 0] * 0.0625f;
  float y1 = rois[r * 4 + 1] * 0.0625f;
  float x2 = rois[r * 4 + 2] * 0.0625f;
  float y2 = rois[r * 4 + 3] * 0.0625f;
  float bw = fmaxf(x2 - x1, 0.1f) / 7.0f;
  float bh = fmaxf(y2 - y1, 0.1f) / 7.0f;
  int c   = t / 49;
  int rem = t - c * 49;
  int gy  = rem / 7;
  int gx  = rem - gy * 7;
  (void)c;
  const float* base = ft + t * HFW;   // chan == t
  float acc = 0.0f;
  for (int sy = 0; sy < 2; sy++) {
    float gyf = (float)gy + (sy ? 0.75f : 0.25f);
    float ys = fminf(fmaxf(y1 + gyf * bh, 0.0f), 159.0f);
    float y0f = floorf(ys);
    float wy = ys - y0f;
    int y0 = (int)y0f;
    int y1i = min(y0 + 1, 159);
    for (int sx = 0; sx < 2; sx++) {
      float gxf = (float)gx + (sx ? 0.75f : 0.25f);
      float xs = fminf(fmaxf(x1 + gxf * bw, 0.0f), 159.0f);
      float x0f = floorf(xs);
      float wx = xs - x0f;
      int x0 = (int)x0f;
      int x1i = min(x0 + 1, 159);
      float v00 = base[y0 * WF_ + x0];
      float v01 = base[y0 * WF_ + x1i];
      float v10 = base[y1i * WF_ + x0];
      float v11 = base[y1i * WF_ + x1i];
      float val = v00 * (1.0f - wy) * (1.0f - wx)
                + v01 * (1.0f - wy) * wx
                + v10 * wy * (1.0f - wx)
                + v11 * wy * wx;
      acc += val;
    }
  }
  float pooled = acc * 0.25f;
  feats[r * FEAT_N + t] = valid[r] ? pooled : 0.0f;
}

// FC1: 300x490 @ 490x2048. Software-pipelined 16-deep w1 loads; feats staged in
// LDS with rows padded to 496 (16B-aligned float4 reads, zero-filled tail).
__global__ void __launch_bounds__(256) k_fc1(const float* __restrict__ feats,
                                             const float* __restrict__ w1,
                                             const float* __restrict__ b1,
                                             float* __restrict__ h)
{
  __shared__ float sf[FC1_MT][FC1_KP];   // 19840 B
  int t = threadIdx.x;
  int n = blockIdx.x * 256 + t;
  int m0 = blockIdx.y * FC1_MT;
  for (int idx = t; idx < FC1_MT * FC1_KP; idx += 256) {
    int mm = idx / FC1_KP;
    int kk = idx - mm * FC1_KP;
    sf[mm][kk] = (kk < FEAT_N) ? feats[(m0 + mm) * FEAT_N + kk] : 0.0f;
  }
  __syncthreads();
  float acc[FC1_MT];
#pragma unroll
  for (int i = 0; i < FC1_MT; i++) acc[i] = 0.0f;
  float wb[16];
#pragma unroll
  for (int u = 0; u < 16; u++) wb[u] = w1[u * HID_N + n];
#pragma unroll 1
  for (int kb = 0; kb < FC1_KP - 16; kb += 16) {
    float wn[16];
    int kn = kb + 16;
#pragma unroll
    for (int u = 0; u < 16; u++)
      wn[u] = (kn + u < FEAT_N) ? w1[(kn + u) * HID_N + n] : 0.0f;
#pragma unroll
    for (int u4 = 0; u4 < 4; u4++) {
#pragma unroll
      for (int i = 0; i < FC1_MT; i++) {
        float4 f = *reinterpret_cast<const float4*>(&sf[i][kb + u4 * 4]);
        acc[i] = fmaf(f.x, wb[u4 * 4 + 0], acc[i]);
        acc[i] = fmaf(f.y, wb[u4 * 4 + 1], acc[i]);
        acc[i] = fmaf(f.z, wb[u4 * 4 + 2], acc[i]);
        acc[i] = fmaf(f.w, wb[u4 * 4 + 3], acc[i]);
      }
    }
#pragma unroll
    for (int u = 0; u < 16; u++) wb[u] = wn[u];
  }
  {
    const int kb = FC1_KP - 16;   // 480: last batch (tail zero-padded)
#pragma unroll
    for (int u4 = 0; u4 < 4; u4++) {
#pragma unroll
      for (int i = 0; i < FC1_MT; i++) {
        float4 f = *reinterpret_cast<const float4*>(&sf[i][kb + u4 * 4]);
        acc[i] = fmaf(f.x, wb[u4 * 4 + 0], acc[i]);
        acc[i] = fmaf(f.y, wb[u4 * 4 + 1], acc[i]);
        acc[i] = fmaf(f.z, wb[u4 * 4 + 2], acc[i]);
        acc[i] = fmaf(f.w, wb[u4 * 4 + 3], acc[i]);
      }
    }
  }
  float b = b1[n];
#pragma unroll
  for (int i = 0; i < FC1_MT; i++) h[(m0 + i) * HID_N + n] = fmaxf(acc[i] + b, 0.0f);
}

__global__ void __launch_bounds__(256) k_fc2(const float* __restrict__ h,
                                             const float* __restrict__ w_cls,
                                             const float* __restrict__ b_cls,
                                             const float* __restrict__ w_bbox,
                                             const float* __restrict__ b_bbox,
                                             const uint32_t* __restrict__ valid,
                                             float* __restrict__ scores3,
                                             float* __restrict__ bbox16)
{
  int r = blockIdx.x;
  int t = threadIdx.x;
  float acc[20];
#pragma unroll
  for (int i = 0; i < 20; i++) acc[i] = 0.0f;
  for (int k = t; k < HID_N; k += 256) {
    float hv = h[r * HID_N + k];
    float4 wc = *reinterpret_cast<const float4*>(w_cls + k * 4);
    acc[0] = fmaf(hv, wc.x, acc[0]);
    acc[1] = fmaf(hv, wc.y, acc[1]);
    acc[2] = fmaf(hv, wc.z, acc[2]);
    acc[3] = fmaf(hv, wc.w, acc[3]);
#pragma unroll
    for (int q = 0; q < 4; q++) {
      float4 wb = *reinterpret_cast<const float4*>(w_bbox + k * 16 + q * 4);
      acc[4 + q * 4 + 0] = fmaf(hv, wb.x, acc[4 + q * 4 + 0]);
      acc[4 + q * 4 + 1] = fmaf(hv, wb.y, acc[4 + q * 4 + 1]);
      acc[4 + q * 4 + 2] = fmaf(hv, wb.z, acc[4 + q * 4 + 2]);
      acc[4 + q * 4 + 3] = fmaf(hv, wb.w, acc[4 + q * 4 + 3]);
    }
  }
#pragma unroll
  for (int off = 32; off > 0; off >>= 1) {
#pragma unroll
    for (int i = 0; i < 20; i++) acc[i] += __shfl_down(acc[i], off);
  }
  __shared__ float red[4][20];
  int wid = t >> 6, lane = t & 63;
  if (lane == 0) {
#pragma unroll
    for (int i = 0; i < 20; i++) red[wid][i] = acc[i];
  }
  __syncthreads();
  if (t == 0) {
    float f[20];
#pragma unroll
    for (int i = 0; i < 20; i++) f[i] = red[0][i] + red[1][i] + red[2][i] + red[3][i];
    float l0 = f[0] + b_cls[0];
    float l1 = f[1] + b_cls[1];
    float l2 = f[2] + b_cls[2];
    float l3 = f[3] + b_cls[3];
    float m = fmaxf(fmaxf(l0, l1), fmaxf(l2, l3));
    float e0 = expf(l0 - m), e1 = expf(l1 - m), e2 = expf(l2 - m), e3 = expf(l3 - m);
    float s = ((e0 + e1) + e2) + e3;
    float vf = valid[r] ? 1.0f : 0.0f;
    scores3[r * 3 + 0] = (e1 / s) * vf;
    scores3[r * 3 + 1] = (e2 / s) * vf;
    scores3[r * 3 + 2] = (e3 / s) * vf;
#pragma unroll
    for (int i = 0; i < 16; i++) bbox16[r * 16 + i] = f[4 + i] + b_bbox[i];
  }
}

// Rank-based rcnn decode+sort: thread t decodes its box + key, ranks against
// all 900 keys (LDS broadcast), writes box/score/idx to slot r. Npos counted
// via LDS atomic BEFORE the single uniform barrier; thread 0 publishes it.
// Slots >= Npos unwritten — never read (scan bounds Npos).
__global__ void __launch_bounds__(1024) k_rc_rank(
    const float* __restrict__ rois,
    const float* __restrict__ scores3,
    const float* __restrict__ bbox16,
    float* __restrict__ sx1, float* __restrict__ sy1,
    float* __restrict__ sx2, float* __restrict__ sy2,
    float* __restrict__ ssc, int* __restrict__ sidx,
    uint32_t* __restrict__ rc_meta)
{
  __shared__ uint64_t keys[1024];
  __shared__ int s_npos;
  int t = threadIdx.x;
  if (t == 0) s_npos = 0;
  uint64_t k = 0;
  float x1 = 0.f, y1 = 0.f, x2 = 0.f, y2 = 0.f, sc = 0.f;
  if (t < RC_N) {
    int r = t / 3;
    int c = t - r * 3;
    float ax1 = rois[r * 4 + 0], ay1 = rois[r * 4 + 1];
    float ax2 = rois[r * 4 + 2], ay2 = rois[r * 4 + 3];
    int cb = (c + 1) * 4;
    float dx = bbox16[r * 16 + cb + 0];
    float dy = bbox16[r * 16 + cb + 1];
    float dw = bbox16[r * 16 + cb + 2];
    float dh = bbox16[r * 16 + cb + 3];
    decode_one(ax1, ay1, ax2, ay2, dx, dy, dw, dh, x1, y1, x2, y2);
    sc = scores3[t];
    if (sc > 0.3f)
      k = ((uint64_t)__float_as_uint(sc) << 32) | (uint32_t)(~(uint32_t)t);
  }
  keys[t] = k;
  if (k != 0) atomicAdd(&s_npos, 1);
  __syncthreads();                       // single uniform barrier for ALL threads
  if (t == 0) rc_meta[0] = (uint32_t)s_npos;
  if (k == 0) return;
  int r = 0;
#pragma unroll 4
  for (int j = 0; j < 1024; j += 4) {
    uint64_t k0 = keys[j + 0];
    uint64_t k1 = keys[j + 1];
    uint64_t k2 = keys[j + 2];
    uint64_t k3 = keys[j + 3];
    r += (k0 > k) ? 1 : 0;
    r += (k1 > k) ? 1 : 0;
    r += (k2 > k) ? 1 : 0;
    r += (k3 > k) ? 1 : 0;
  }
  sx1[r] = x1; sy1[r] = y1; sx2[r] = x2; sy2[r] = y2;
  ssc[r] = sc; sidx[r] = t;
}

// 900x15-word IoU>0.5 bitmask in sorted index space (upper triangle only) + diag.
__global__ void __launch_bounds__(256) k_rc_mask(
    const float* __restrict__ sx1, const float* __restrict__ sy1,
    const float* __restrict__ sx2, const float* __restrict__ sy2,
    uint64_t* __restrict__ rcmask, uint64_t* __restrict__ rcdiag)
{
  __shared__ float s1[RC_N], s2[RC_N], s3[RC_N], s4[RC_N];  // 14.4 KB
  int t = threadIdx.x;
  for (int e = t; e < RC_N; e += 256) {
    s1[e] = sx1[e]; s2[e] = sy1[e]; s3[e] = sx2[e]; s4[e] = sy2[e];
  }
  __syncthreads();
  int task = blockIdx.x * 256 + t;
  if (task >= RC_N * RNW) return;
  int row = task / RNW;
  int w   = task - row * RNW;
  if ((w + 1) * 64 <= row) {
    rcmask[(size_t)row * RNW + w] = 0;
    return;
  }
  float ax1 = s1[row], ay1 = s2[row], ax2 = s3[row], ay2 = s4[row];
  float areaA;
  {
#pragma clang fp contract(off)
    areaA = fmaxf((ax2 - ax1) + 1.0f, 0.0f) * fmaxf((ay2 - ay1) + 1.0f, 0.0f);
  }
  int j0 = w << 6;
  uint64_t bits = 0;
  for (int off = 0; off < 64; off++) {
    int jj = (off + t) & 63;
    int j = j0 + jj;
    if (j < RC_N) {
      float iou = iou_ref(ax1, ay1, ax2, ay2, areaA, s1[j], s2[j], s3[j], s4[j]);
      if (iou > 0.5f) bits |= 1ull << jj;
    }
  }
  rcmask[(size_t)row * RNW + w] = bits;
  if (w == (row >> 6)) rcdiag[row] = bits;
}

// ctz-enumeration scan over sorted rcnn candidates; whole mask + diag in LDS.
__global__ void __launch_bounds__(256) k_rc_scan(
    const float* __restrict__ sx1, const float* __restrict__ sy1,
    const float* __restrict__ sx2, const float* __restrict__ sy2,
    const float* __restrict__ ssc, const int* __restrict__ sidx,
    const uint32_t* __restrict__ rc_meta,
    const uint64_t* __restrict__ rcmask,
    const uint64_t* __restrict__ rcdiag,
    float* __restrict__ out)
{
  __shared__ uint64_t rowstage[RC_N * RNW];   // 108000 B
  __shared__ uint64_t sdiag[RC_N];            // 7200 B
  __shared__ int keepPos[FIN_N];
  __shared__ int s_nk;
  int t = threadIdx.x;
  for (int e = t; e < RC_N * RNW; e += 256) rowstage[e] = rcmask[e];
  for (int e = t; e < RC_N; e += 256) sdiag[e] = rcdiag[e];
  __syncthreads();
  if (t < 64) {
    int lane = t;
    int Npos = (int)min(rc_meta[0], (uint32_t)RC_N);
    uint64_t sup = 0, pend = 0;
    int nk = 0;
    int nwords = (Npos + 63) >> 6;
    for (int w = 0; w < nwords && nk < FIN_N; w++) {
      sup |= pend; pend = 0;
      uint64_t cw = (uint64_t)__shfl((unsigned long long)sup, w);
      int lim = Npos - (w << 6);
      uint64_t range = (lim >= 64) ? ~0ull : ((1ull << lim) - 1ull);
      uint64_t rem = (~cw) & range;
      while (rem && nk < FIN_N) {
        int b = __builtin_ctzll(rem);
        int i = (w << 6) + b;
        if (lane == 0) keepPos[nk] = i;
        nk++;
        uint64_t roww = sdiag[i];
        uint64_t rowl = (lane < RNW) ? rowstage[i * RNW + lane] : 0;
        sup |= pend;
        pend = rowl;
        rem &= ~(roww | (1ull << b));
      }
    }
    sup |= pend;
    if (lane == 0) s_nk = nk;
  }
  __syncthreads();
  int nk = s_nk;
  for (int k = t; k < nk; k += 256) {
    int i = keepPos[k];
    int m = sidx[i];
    out[k * 6 + 0] = sx1[i];
    out[k * 6 + 1] = sy1[i];
    out[k * 6 + 2] = sx2[i];
    out[k * 6 + 3] = sy2[i];
    out[k * 6 + 4] = ssc[i];
    out[k * 6 + 5] = (float)(m - (m / 3) * 3 + 1);
  }
  for (int e = nk * 6 + t; e < FIN_N * 6; e += 256) out[e] = 0.0f;
}

extern "C" void kernel_launch(void* const* d_in, const int* in_sizes, int n_in,
                              void* d_out, int out_size, void* d_ws, size_t ws_size,
                              hipStream_t stream)
{
  (void)in_sizes; (void)n_in; (void)out_size; (void)ws_size;
  const float* rpn_cls  = (const float*)d_in[0];
  const float* rpn_bbox = (const float*)d_in[1];
  const float* ft       = (const float*)d_in[2];
  const float* w1       = (const float*)d_in[3];
  const float* b1       = (const float*)d_in[4];
  const float* w_cls    = (const float*)d_in[5];
  const float* b_cls    = (const float*)d_in[6];
  const float* w_bbox   = (const float*)d_in[7];
  const float* b_bbox   = (const float*)d_in[8];
  float* out = (float*)d_out;

  char* ws = (char*)d_ws;
  size_t off = 0;
  auto alloc = [&](size_t bytes) -> void* {
    void* p = (void*)(ws + off);
    off += (bytes + 15) & ~(size_t)15;
    return p;
  };
  uint32_t* hist1  = (uint32_t*)alloc(65536 * 4);
  uint32_t* hist2  = (uint32_t*)alloc(65536 * 4);
  uint32_t* meta   = (uint32_t*)alloc(32 * 4);        // contiguous with hists
  float*    scores = (float*)alloc((size_t)NTOT * 4);
  uint64_t* gt     = (uint64_t*)alloc(3008 * 8);
  uint64_t* tie    = (uint64_t*)alloc(TIE_CAP * 8);
  float*    bxx1 = (float*)alloc(PRE_N * 4);
  float*    bxy1 = (float*)alloc(PRE_N * 4);
  float*    bxx2 = (float*)alloc(PRE_N * 4);
  float*    bxy2 = (float*)alloc(PRE_N * 4);
  float*    rois  = (float*)alloc(KEEP_N * 4 * 4);
  uint32_t* valid = (uint32_t*)alloc(KEEP_N * 4);
  float*    feats = (float*)alloc((size_t)KEEP_N * FEAT_N * 4);
  float*    hbuf  = (float*)alloc((size_t)KEEP_N * HID_N * 4);
  float*    scores3 = (float*)alloc(RC_N * 4);
  float*    bbox16  = (float*)alloc(KEEP_N * 16 * 4);
  float*    sx1 = (float*)alloc(RC_N * 4);
  float*    sy1 = (float*)alloc(RC_N * 4);
  float*    sx2 = (float*)alloc(RC_N * 4);
  float*    sy2 = (float*)alloc(RC_N * 4);
  float*    ssc = (float*)alloc(RC_N * 4);
  int*      sidx = (int*)alloc(RC_N * 4);
  uint32_t* rc_meta = (uint32_t*)alloc(16 * 4);
  uint64_t* rowmask = (uint64_t*)alloc((size_t)3008 * NW * 8);
  uint64_t* diag    = (uint64_t*)alloc(3008 * 8);
  uint64_t* rcmask  = (uint64_t*)alloc((size_t)RC_N * RNW * 8);
  uint64_t* rcdiag  = (uint64_t*)alloc(904 * 8);

  k_decode_score<<<NTOT / 256, 256, 0, stream>>>(rpn_cls, rpn_bbox, scores, hist1);
  k_hist_hi<<<NTOT / 256, 256, 0, stream>>>(scores, hist1);
  k_findbin1<<<1, 1024, 0, stream>>>(hist1, meta);
  k_hist_lo<<<NTOT / 256, 256, 0, stream>>>(scores, meta, hist2);
  k_findT<<<1, 1024, 0, stream>>>(hist2, meta);
  k_compact<<<NTOT / 256, 256, 0, stream>>>(scores, meta, gt, tie, meta + 8);
  k_rank_gather<<<16, 256, 0, stream>>>(gt, tie, meta + 8, rpn_bbox,
                                        bxx1, bxy1, bxx2, bxy2);
  k_iou_mask<<<(PRE_N * NW + 255) / 256, 256, 0, stream>>>(bxx1, bxy1, bxx2, bxy2,
                                                           rowmask, diag);
  k_rpn_scan<<<1, 256, 0, stream>>>(bxx1, bxy1, bxx2, bxy2, meta + 8,
                                    rowmask, diag, rois, valid);
  k_psroi<<<KEEP_N, 512, 0, stream>>>(ft, rois, valid, feats);
  k_fc1<<<dim3(HID_N / 256, KEEP_N / FC1_MT), 256, 0, stream>>>(feats, w1, b1, hbuf);
  k_fc2<<<KEEP_N, 256, 0, stream>>>(hbuf, w_cls, b_cls, w_bbox, b_bbox, valid,
                                    scores3, bbox16);
  k_rc_rank<<<1, 1024, 0, stream>>>(rois, scores3, bbox16,
                                    sx1, sy1, sx2, sy2, ssc, sidx, rc_meta);
  k_rc_mask<<<(RC_N * RNW + 255) / 256, 256, 0, stream>>>(sx1, sy1, sx2, sy2,
                                                          rcmask, rcdiag);
  k_rc_scan<<<1, 256, 0, stream>>>(sx1, sy1, sx2, sy2, ssc, sidx, rc_meta,
                                   rcmask, rcdiag, out);
}

// Round 11
// 450.648 us; speedup vs baseline: 1.0443x; 1.0443x over previous
//
#include <hip/hip_runtime.h>
#include <stdint.h>

#define HF_ 160
#define WF_ 160
#define HFW 25600          // 160*160
#define A_N 15
#define NTOT 384000        // 15*160*160
#define PRE_N 3000
#define KEEP_N 300
#define FEAT_N 490
#define HID_N 2048
#define RC_N 900
#define FIN_N 100
#define TIE_CAP 1024
#define NW 47              // ceil(3000/64) uint64 words per rpn mask row
#define RNW 15             // ceil(900/64) uint64 words per rcnn mask row
#define FC1_MT 10          // rows per fc1 block
#define FC1_KP 496         // K padded to multiple of 16 (16B-aligned float4 rows)
#define ZN (65536 * 2 + 32) // hist1+hist2+meta words to zero

// Anchor half-extents, float64-derived literals (r in {0.5,1,2} x s in {2,4,8,16,32})
__constant__ float c_hw[15] = {
  22.627416997969522f, 45.254833995939045f, 90.509667991878090f, 181.01933598375618f, 362.03867196751236f,
  16.0f, 32.0f, 64.0f, 128.0f, 256.0f,
  11.313708498984761f, 22.627416997969522f, 45.254833995939045f, 90.509667991878090f, 181.01933598375618f
};
__constant__ float c_hh[15] = {
  11.313708498984761f, 22.627416997969522f, 45.254833995939045f, 90.509667991878090f, 181.01933598375618f,
  16.0f, 32.0f, 64.0f, 128.0f, 256.0f,
  22.627416997969522f, 45.254833995939045f, 90.509667991878090f, 181.01933598375618f, 362.03867196751236f
};

__device__ __forceinline__ void decode_one(
    float ax1, float ay1, float ax2, float ay2,
    float dx, float dy, float dw, float dh,
    float& ox1, float& oy1, float& ox2, float& oy2)
{
#pragma clang fp contract(off)
  float wa = (ax2 - ax1) + 1.0f;
  float ha = (ay2 - ay1) + 1.0f;
  float cxa = ax1 + 0.5f * wa;
  float cya = ay1 + 0.5f * ha;
  float d0 = dx * 0.1f;
  float d1 = dy * 0.1f;
  float d2 = dw * 0.2f;
  float d3 = dh * 0.2f;
  float cx = d0 * wa + cxa;
  float cy = d1 * ha + cya;
  float w  = wa * expf(fminf(d2, 4.0f));
  float h  = ha * expf(fminf(d3, 4.0f));
  float x1 = cx - 0.5f * w;
  float y1 = cy - 0.5f * h;
  float x2 = cx + 0.5f * w;
  float y2 = cy + 0.5f * h;
  ox1 = fminf(fmaxf(x1, 0.0f), 2559.0f);
  oy1 = fminf(fmaxf(y1, 0.0f), 2559.0f);
  ox2 = fminf(fmaxf(x2, 0.0f), 2559.0f);
  oy2 = fminf(fmaxf(y2, 0.0f), 2559.0f);
}

__device__ __forceinline__ float iou_ref(
    float ax1, float ay1, float ax2, float ay2, float areaA,
    float bx1, float by1, float bx2, float by2)
{
#pragma clang fp contract(off)
  float ix1 = fmaxf(ax1, bx1);
  float iy1 = fmaxf(ay1, by1);
  float ix2 = fminf(ax2, bx2);
  float iy2 = fminf(ay2, by2);
  float iw = fmaxf((ix2 - ix1) + 1.0f, 0.0f);
  float ih = fmaxf((iy2 - iy1) + 1.0f, 0.0f);
  float inter = iw * ih;
  float areaB = fmaxf((bx2 - bx1) + 1.0f, 0.0f) * fmaxf((by2 - by1) + 1.0f, 0.0f);
  float den = fmaxf(areaA + areaB - inter, 1e-6f);
  return inter / den;
}

// Decode all anchors, apply (w>=8, h>=8, score>0.2) filter; write filtered
// scores. Also zeroes hist1/hist2/meta (fused former k_zero).
__global__ void k_decode_score(const float* __restrict__ cls,
                               const float* __restrict__ bbox,
                               float* __restrict__ scores,
                               uint32_t* __restrict__ histzero)
{
  int e = blockIdx.x * 256 + threadIdx.x;
  if (e < ZN) histzero[e] = 0u;
  if (e >= NTOT) return;
  int a   = e / HFW;
  int rem = e - a * HFW;
  int i   = rem / WF_;
  int j   = rem - i * WF_;
  float score = cls[(A_N + a) * HFW + rem];
  float gx = (float)(j * 16);
  float gy = (float)(i * 16);
  float hw = c_hw[a], hh = c_hh[a];
  float dx = bbox[(a * 4 + 0) * HFW + rem];
  float dy = bbox[(a * 4 + 1) * HFW + rem];
  float dw = bbox[(a * 4 + 2) * HFW + rem];
  float dh = bbox[(a * 4 + 3) * HFW + rem];
  float x1, y1, x2, y2;
  decode_one(gx - hw, gy - hh, gx + hw, gy + hh, dx, dy, dw, dh, x1, y1, x2, y2);
  float bw, bh;
  {
#pragma clang fp contract(off)
    bw = (x2 - x1) + 1.0f;
    bh = (y2 - y1) + 1.0f;
  }
  bool ok = (bw >= 8.0f) && (bh >= 8.0f) && (score > 0.2f);
  scores[e] = ok ? score : 0.0f;
}

// Histogram of high-16 float bits (positive scores); LDS window covers [0.125,2).
__global__ void k_hist_hi(const float* __restrict__ scores, uint32_t* __restrict__ hist)
{
  __shared__ uint32_t lh[512];
  int t = threadIdx.x;
  for (int i = t; i < 512; i += 256) lh[i] = 0u;
  __syncthreads();
  int e = blockIdx.x * 256 + t;
  if (e < NTOT) {
    float s = scores[e];
    if (s > 0.0f) {
      uint32_t b = __float_as_uint(s) >> 16;
      if (b >= 0x3E00u && b < 0x4000u) atomicAdd(&lh[b - 0x3E00u], 1u);
      else atomicAdd(&hist[b], 1u);
    }
  }
  __syncthreads();
  for (int i = t; i < 512; i += 256) {
    uint32_t v = lh[i];
    if (v) atomicAdd(&hist[0x3E00u + i], v);
  }
}

// Parallel selection of the hi-16 threshold bin.
// meta: [0]=B1 [1]=K_rem [2]=nocross [3]=T
__global__ void __launch_bounds__(1024) k_findbin1(const uint32_t* __restrict__ hist,
                                                   uint32_t* __restrict__ meta)
{
  __shared__ uint32_t sfx[1024];
  __shared__ int s_chunk;
  __shared__ uint32_t s_exc;
  int t = threadIdx.x;
  if (t == 0) s_chunk = -1;
  const uint32_t* hp = hist + t * 64;
  uint32_t s = 0;
#pragma unroll
  for (int b = 0; b < 64; b++) s += hp[b];
  sfx[t] = s;
  __syncthreads();
  for (int d = 1; d < 1024; d <<= 1) {
    uint32_t v = (t + d < 1024) ? sfx[t + d] : 0u;
    __syncthreads();
    sfx[t] += v;
    __syncthreads();
  }
  uint32_t inc = sfx[t];
  uint32_t exc = (t < 1023) ? sfx[t + 1] : 0u;
  if (exc < (uint32_t)PRE_N && inc >= (uint32_t)PRE_N) { s_chunk = t; s_exc = exc; }
  __syncthreads();
  int c = s_chunk;
  if (c < 0) {
    if (t == 0) { meta[0] = 0u; meta[1] = 0u; meta[2] = 1u; }
    return;
  }
  if (t < 64) {
    uint32_t h = hist[c * 64 + t];
    uint32_t v = h;
#pragma unroll
    for (int d = 1; d < 64; d <<= 1) {
      uint32_t o = (uint32_t)__shfl_down((int)v, d);
      v += (t + d < 64) ? o : 0u;
    }
    uint32_t before = s_exc + (v - h);   // keys strictly above bin (c*64+t)
    if (before < (uint32_t)PRE_N && before + h >= (uint32_t)PRE_N) {
      meta[0] = (uint32_t)(c * 64 + t);
      meta[1] = (uint32_t)PRE_N - before;
      meta[2] = 0u;
    }
  }
}

__global__ void k_hist_lo(const float* __restrict__ scores,
                          const uint32_t* __restrict__ meta,
                          uint32_t* __restrict__ hist2)
{
  if (meta[2]) return;
  uint32_t B1 = meta[0];
  int e = blockIdx.x * 256 + threadIdx.x;
  if (e >= NTOT) return;
  float s = scores[e];
  if (s <= 0.0f) return;
  uint32_t bits = __float_as_uint(s);
  if ((bits >> 16) == B1) atomicAdd(&hist2[bits & 0xFFFFu], 1u);
}

// Parallel selection of the lo-16 threshold within bin B1.
__global__ void __launch_bounds__(1024) k_findT(const uint32_t* __restrict__ hist2,
                                                uint32_t* __restrict__ meta)
{
  if (meta[2]) { if (threadIdx.x == 0) meta[3] = 0u; return; }
  __shared__ uint32_t sfx[1024];
  __shared__ int s_chunk;
  __shared__ uint32_t s_exc;
  int t = threadIdx.x;
  if (t == 0) s_chunk = -1;
  uint32_t K = meta[1];
  const uint32_t* hp = hist2 + t * 64;
  uint32_t s = 0;
#pragma unroll
  for (int b = 0; b < 64; b++) s += hp[b];
  sfx[t] = s;
  __syncthreads();
  for (int d = 1; d < 1024; d <<= 1) {
    uint32_t v = (t + d < 1024) ? sfx[t + d] : 0u;
    __syncthreads();
    sfx[t] += v;
    __syncthreads();
  }
  uint32_t inc = sfx[t];
  uint32_t exc = (t < 1023) ? sfx[t + 1] : 0u;
  if (exc < K && inc >= K) { s_chunk = t; s_exc = exc; }
  __syncthreads();
  int c = s_chunk;
  if (c < 0) { if (t == 0) meta[3] = 0u; return; }   // should not happen
  if (t < 64) {
    uint32_t h = hist2[c * 64 + t];
    uint32_t v = h;
#pragma unroll
    for (int d = 1; d < 64; d <<= 1) {
      uint32_t o = (uint32_t)__shfl_down((int)v, d);
      v += (t + d < 64) ? o : 0u;
    }
    uint32_t before = s_exc + (v - h);
    if (before < K && before + h >= K)
      meta[3] = (meta[0] << 16) | (uint32_t)(c * 64 + t);
  }
}

// key = scoreBits<<32 | ~idx  → descending order == (score desc, idx asc) == jax top_k order
__global__ void k_compact(const float* __restrict__ scores,
                          const uint32_t* __restrict__ meta,
                          uint64_t* __restrict__ gt,
                          uint64_t* __restrict__ tie,
                          uint32_t* __restrict__ cnts)
{
  int e = blockIdx.x * 256 + threadIdx.x;
  if (e >= NTOT) return;
  float s = scores[e];
  if (s <= 0.0f) return;
  uint32_t bits = __float_as_uint(s);
  uint32_t T = meta[3];
  uint64_t key = ((uint64_t)bits << 32) | (uint32_t)(~(uint32_t)e);
  if (bits > T) {
    uint32_t p = atomicAdd(&cnts[0], 1u);
    if (p < (uint32_t)PRE_N) gt[p] = key;
  } else if (bits == T) {
    uint32_t p = atomicAdd(&cnts[1], 1u);
    if (p < (uint32_t)TIE_CAP) tie[p] = key;
  }
}

// Rank-based sort+gather: position = #{keys > mine} (keys unique). 63 blocks
// x 64 threads → ONE wave per CU so the 4096-deep uniform-LDS-read rank loop
// isn't serialized behind sibling waves on the same LDS pipe (round-10 lesson).
__global__ void __launch_bounds__(64) k_rank_gather(
    const uint64_t* __restrict__ gt,
    const uint64_t* __restrict__ tie,
    const uint32_t* __restrict__ cnts,
    const float* __restrict__ bbox,
    float* __restrict__ bxx1, float* __restrict__ bxy1,
    float* __restrict__ bxx2, float* __restrict__ bxy2)
{
  __shared__ uint64_t keys[4096];   // 32 KB
  int t = threadIdx.x;
  uint32_t ngt = min(cnts[0], (uint32_t)PRE_N);
  uint32_t nte = min(cnts[1], (uint32_t)TIE_CAP);
  uint32_t M = ngt + nte;           // <= 4024
  for (int s = t; s < 4096; s += 64) {
    uint64_t k = 0;
    if ((uint32_t)s < ngt) k = gt[s];
    else if ((uint32_t)s < M) k = tie[s - ngt];
    keys[s] = k;
  }
  __syncthreads();
  int e = blockIdx.x * 64 + t;      // < 4032
  uint64_t my = keys[e];
  if (my == 0) return;
  int MM = (int)((M + 3u) & ~3u);   // keys >= M are 0, never > my
  int r = 0;
  for (int j = 0; j < MM; j += 4) {
    uint64_t k0 = keys[j + 0];      // uniform address → LDS broadcast
    uint64_t k1 = keys[j + 1];
    uint64_t k2 = keys[j + 2];
    uint64_t k3 = keys[j + 3];
    r += (k0 > my) ? 1 : 0;
    r += (k1 > my) ? 1 : 0;
    r += (k2 > my) ? 1 : 0;
    r += (k3 > my) ? 1 : 0;
  }
  if (r >= PRE_N) return;
  int idx = (int)(~(uint32_t)(my & 0xFFFFFFFFull));
  int a   = idx / HFW;
  int rem = idx - a * HFW;
  int i   = rem / WF_;
  int j   = rem - i * WF_;
  float gx = (float)(j * 16);
  float gy = (float)(i * 16);
  float hw = c_hw[a], hh = c_hh[a];
  float dx = bbox[(a * 4 + 0) * HFW + rem];
  float dy = bbox[(a * 4 + 1) * HFW + rem];
  float dw = bbox[(a * 4 + 2) * HFW + rem];
  float dh = bbox[(a * 4 + 3) * HFW + rem];
  float x1, y1, x2, y2;
  decode_one(gx - hw, gy - hh, gx + hw, gy + hh, dx, dy, dw, dh, x1, y1, x2, y2);
  bxx1[r] = x1; bxy1[r] = y1; bxx2[r] = x2; bxy2[r] = y2;
}

// Parallel IoU mask (upper triangle only — rows only suppress later candidates).
// Also emits diag[row] = word (row>>6) of row (the scan's critical-path word).
__global__ void __launch_bounds__(256) k_iou_mask(
    const float* __restrict__ bxx1, const float* __restrict__ bxy1,
    const float* __restrict__ bxx2, const float* __restrict__ bxy2,
    uint64_t* __restrict__ rowmask, uint64_t* __restrict__ diag)
{
  __shared__ float s1[PRE_N], s2[PRE_N], s3[PRE_N], s4[PRE_N];  // 48 KB
  int t = threadIdx.x;
  for (int e = t; e < PRE_N; e += 256) {
    s1[e] = bxx1[e]; s2[e] = bxy1[e]; s3[e] = bxx2[e]; s4[e] = bxy2[e];
  }
  __syncthreads();
  int task = blockIdx.x * 256 + t;
  if (task >= PRE_N * NW) return;
  int row = task / NW;
  int w   = task - row * NW;
  if ((w + 1) * 64 <= row) {       // strictly-lower word: only OR'd with 0s
    rowmask[(size_t)row * NW + w] = 0;
    return;
  }
  float ax1 = s1[row], ay1 = s2[row], ax2 = s3[row], ay2 = s4[row];
  float areaA;
  {
#pragma clang fp contract(off)
    areaA = fmaxf((ax2 - ax1) + 1.0f, 0.0f) * fmaxf((ay2 - ay1) + 1.0f, 0.0f);
  }
  int j0 = w << 6;
  uint64_t bits = 0;
  for (int off = 0; off < 64; off++) {
    int jj = (off + t) & 63;
    int j = j0 + jj;
    if (j < PRE_N) {
      float iou = iou_ref(ax1, ay1, ax2, ay2, areaA, s1[j], s2[j], s3[j], s4[j]);
      if (iou > 0.7f) bits |= 1ull << jj;
    }
  }
  rowmask[(size_t)row * NW + w] = bits;
  if (w == (row >> 6)) diag[row] = bits;
}

// ctz-enumeration greedy scan v3 (single wave):
//  - per word: lane b holds diag of candidate w*64+b (one coalesced LDS read);
//    per-keep chain = ctz + shfl-broadcast (~50 cy), no LDS load on the chain.
//  - kept rows folded into sup from L2 in 8-wide batches (one waitcnt each),
//    at word end — before any later word's cw is computed. Same semantics as
//    the proven v2 (diag handles same-word, full rows handle cross-word).
__global__ void __launch_bounds__(64) k_rpn_scan(
    const float* __restrict__ bxx1, const float* __restrict__ bxy1,
    const float* __restrict__ bxx2, const float* __restrict__ bxy2,
    const uint32_t* __restrict__ cnts,
    const uint64_t* __restrict__ rowmask,
    const uint64_t* __restrict__ diag,
    float* __restrict__ rois, uint32_t* __restrict__ valid)
{
  __shared__ uint64_t sdiag[PRE_N];   // 24 KB
  __shared__ int keepIdx[KEEP_N];
  int lane = threadIdx.x;
  for (int e = lane; e < PRE_N; e += 64) sdiag[e] = diag[e];
  __syncthreads();
  uint32_t Mp = min(cnts[0] + min(cnts[1], (uint32_t)TIE_CAP), (uint32_t)PRE_N);
  uint64_t sup = 0;
  int nk = 0;
  int nwords = (int)((Mp + 63u) >> 6);
  for (int w = 0; w < nwords && nk < KEEP_N; w++) {
    uint64_t cw = (uint64_t)__shfl((unsigned long long)sup, w);
    int ci = (w << 6) + lane;
    uint64_t dg = (ci < (int)Mp) ? sdiag[ci] : 0;
    int lim = (int)Mp - (w << 6);
    uint64_t range = (lim >= 64) ? ~0ull : ((1ull << lim) - 1ull);
    uint64_t rem = (~cw) & range;
    uint64_t keepbits = 0;
    while (rem && nk < KEEP_N) {
      int b = __builtin_ctzll(rem);
      keepbits |= 1ull << b;
      if (lane == 0) keepIdx[nk] = (w << 6) + b;
      nk++;
      uint64_t roww = (uint64_t)__shfl((unsigned long long)dg, b);
      rem &= ~(roww | (1ull << b));
    }
    while (keepbits) {
      uint64_t r0 = 0, r1 = 0, r2 = 0, r3 = 0, r4 = 0, r5 = 0, r6 = 0, r7 = 0;
      int b;
      if (keepbits) { b = __builtin_ctzll(keepbits); keepbits &= keepbits - 1;
        if (lane < NW) r0 = rowmask[(size_t)((w << 6) + b) * NW + lane]; }
      if (keepbits) { b = __builtin_ctzll(keepbits); keepbits &= keepbits - 1;
        if (lane < NW) r1 = rowmask[(size_t)((w << 6) + b) * NW + lane]; }
      if (keepbits) { b = __builtin_ctzll(keepbits); keepbits &= keepbits - 1;
        if (lane < NW) r2 = rowmask[(size_t)((w << 6) + b) * NW + lane]; }
      if (keepbits) { b = __builtin_ctzll(keepbits); keepbits &= keepbits - 1;
        if (lane < NW) r3 = rowmask[(size_t)((w << 6) + b) * NW + lane]; }
      if (keepbits) { b = __builtin_ctzll(keepbits); keepbits &= keepbits - 1;
        if (lane < NW) r4 = rowmask[(size_t)((w << 6) + b) * NW + lane]; }
      if (keepbits) { b = __builtin_ctzll(keepbits); keepbits &= keepbits - 1;
        if (lane < NW) r5 = rowmask[(size_t)((w << 6) + b) * NW + lane]; }
      if (keepbits) { b = __builtin_ctzll(keepbits); keepbits &= keepbits - 1;
        if (lane < NW) r6 = rowmask[(size_t)((w << 6) + b) * NW + lane]; }
      if (keepbits) { b = __builtin_ctzll(keepbits); keepbits &= keepbits - 1;
        if (lane < NW) r7 = rowmask[(size_t)((w << 6) + b) * NW + lane]; }
      sup |= ((r0 | r1) | (r2 | r3)) | ((r4 | r5) | (r6 | r7));
    }
  }
  __syncthreads();
  for (int k = lane; k < nk; k += 64) {
    int i = keepIdx[k];
    rois[k * 4 + 0] = bxx1[i];
    rois[k * 4 + 1] = bxy1[i];
    rois[k * 4 + 2] = bxx2[i];
    rois[k * 4 + 3] = bxy2[i];
    valid[k] = 1u;
  }
  for (int e = nk * 4 + lane; e < KEEP_N * 4; e += 64) rois[e] = 0.0f;
  for (int e = nk + lane; e < KEEP_N; e += 64) valid[e] = 0u;
}

__global__ void __launch_bounds__(512) k_psroi(const float* __restrict__ ft,
                                               const float* __restrict__ rois,
                                               const uint32_t* __restrict__ valid,
                                               float* __restrict__ feats)
{
#pragma clang fp contract(off)
  int r = blockIdx.x;
  int t = threadIdx.x;
  if (t >= FEAT_N) return;
  float x1 = rois[r * 4 + 0] * 0.0625f;
  float y1 = rois[r * 4 + 1] * 0.0625f;
  float x2 = rois[r * 4 + 2] * 0.0625f;
  float y2 = rois[r * 4 + 3] * 0.0625f;
  float bw = fmaxf(x2 - x1, 0.1f) / 7.0f;
  float bh = fmaxf(y2 - y1, 0.1f) / 7.0f;
  int c   = t / 49;
  int rem = t - c * 49;
  int gy  = rem / 7;
  int gx  = rem - gy * 7;
  (void)c;
  const float* base = ft + t * HFW;   // chan == t
  float acc = 0.0f;
  for (int sy = 0; sy < 2; sy++) {
    float gyf = (float)gy + (sy ? 0.75f : 0.25f);
    float ys = fminf(fmaxf(y1 + gyf * bh, 0.0f), 159.0f);
    float y0f = floorf(ys);
    float wy = ys - y0f;
    int y0 = (int)y0f;
    int y1i = min(y0 + 1, 159);
    for (int sx = 0; sx < 2; sx++) {
      float gxf = (float)gx + (sx ? 0.75f : 0.25f);
      float xs = fminf(fmaxf(x1 + gxf * bw, 0.0f), 159.0f);
      float x0f = floorf(xs);
      float wx = xs - x0f;
      int x0 = (int)x0f;
      int x1i = min(x0 + 1, 159);
      float v00 = base[y0 * WF_ + x0];
      float v01 = base[y0 * WF_ + x1i];
      float v10 = base[y1i * WF_ + x0];
      float v11 = base[y1i * WF_ + x1i];
      float val = v00 * (1.0f - wy) * (1.0f - wx)
                + v01 * (1.0f - wy) * wx
                + v10 * wy * (1.0f - wx)
                + v11 * wy * wx;
      acc += val;
    }
  }
  float pooled = acc * 0.25f;
  feats[r * FEAT_N + t] = valid[r] ? pooled : 0.0f;
}

// FC1: 300x490 @ 490x2048. Software-pipelined 16-deep w1 loads; feats staged in
// LDS with rows padded to 496 (16B-aligned float4 reads, zero-filled tail).
__global__ void __launch_bounds__(256) k_fc1(const float* __restrict__ feats,
                                             const float* __restrict__ w1,
                                             const float* __restrict__ b1,
                                             float* __restrict__ h)
{
  __shared__ float sf[FC1_MT][FC1_KP];   // 19840 B
  int t = threadIdx.x;
  int n = blockIdx.x * 256 + t;
  int m0 = blockIdx.y * FC1_MT;
  for (int idx = t; idx < FC1_MT * FC1_KP; idx += 256) {
    int mm = idx / FC1_KP;
    int kk = idx - mm * FC1_KP;
    sf[mm][kk] = (kk < FEAT_N) ? feats[(m0 + mm) * FEAT_N + kk] : 0.0f;
  }
  __syncthreads();
  float acc[FC1_MT];
#pragma unroll
  for (int i = 0; i < FC1_MT; i++) acc[i] = 0.0f;
  float wb[16];
#pragma unroll
  for (int u = 0; u < 16; u++) wb[u] = w1[u * HID_N + n];
#pragma unroll 1
  for (int kb = 0; kb < FC1_KP - 16; kb += 16) {
    float wn[16];
    int kn = kb + 16;
#pragma unroll
    for (int u = 0; u < 16; u++)
      wn[u] = (kn + u < FEAT_N) ? w1[(kn + u) * HID_N + n] : 0.0f;
#pragma unroll
    for (int u4 = 0; u4 < 4; u4++) {
#pragma unroll
      for (int i = 0; i < FC1_MT; i++) {
        float4 f = *reinterpret_cast<const float4*>(&sf[i][kb + u4 * 4]);
        acc[i] = fmaf(f.x, wb[u4 * 4 + 0], acc[i]);
        acc[i] = fmaf(f.y, wb[u4 * 4 + 1], acc[i]);
        acc[i] = fmaf(f.z, wb[u4 * 4 + 2], acc[i]);
        acc[i] = fmaf(f.w, wb[u4 * 4 + 3], acc[i]);
      }
    }
#pragma unroll
    for (int u = 0; u < 16; u++) wb[u] = wn[u];
  }
  {
    const int kb = FC1_KP - 16;   // 480: last batch (tail zero-padded)
#pragma unroll
    for (int u4 = 0; u4 < 4; u4++) {
#pragma unroll
      for (int i = 0; i < FC1_MT; i++) {
        float4 f = *reinterpret_cast<const float4*>(&sf[i][kb + u4 * 4]);
        acc[i] = fmaf(f.x, wb[u4 * 4 + 0], acc[i]);
        acc[i] = fmaf(f.y, wb[u4 * 4 + 1], acc[i]);
        acc[i] = fmaf(f.z, wb[u4 * 4 + 2], acc[i]);
        acc[i] = fmaf(f.w, wb[u4 * 4 + 3], acc[i]);
      }
    }
  }
  float b = b1[n];
#pragma unroll
  for (int i = 0; i < FC1_MT; i++) h[(m0 + i) * HID_N + n] = fmaxf(acc[i] + b, 0.0f);
}

__global__ void __launch_bounds__(256) k_fc2(const float* __restrict__ h,
                                             const float* __restrict__ w_cls,
                                             const float* __restrict__ b_cls,
                                             const float* __restrict__ w_bbox,
                                             const float* __restrict__ b_bbox,
                                             const uint32_t* __restrict__ valid,
                                             float* __restrict__ scores3,
                                             float* __restrict__ bbox16)
{
  int r = blockIdx.x;
  int t = threadIdx.x;
  float acc[20];
#pragma unroll
  for (int i = 0; i < 20; i++) acc[i] = 0.0f;
  for (int k = t; k < HID_N; k += 256) {
    float hv = h[r * HID_N + k];
    float4 wc = *reinterpret_cast<const float4*>(w_cls + k * 4);
    acc[0] = fmaf(hv, wc.x, acc[0]);
    acc[1] = fmaf(hv, wc.y, acc[1]);
    acc[2] = fmaf(hv, wc.z, acc[2]);
    acc[3] = fmaf(hv, wc.w, acc[3]);
#pragma unroll
    for (int q = 0; q < 4; q++) {
      float4 wb = *reinterpret_cast<const float4*>(w_bbox + k * 16 + q * 4);
      acc[4 + q * 4 + 0] = fmaf(hv, wb.x, acc[4 + q * 4 + 0]);
      acc[4 + q * 4 + 1] = fmaf(hv, wb.y, acc[4 + q * 4 + 1]);
      acc[4 + q * 4 + 2] = fmaf(hv, wb.z, acc[4 + q * 4 + 2]);
      acc[4 + q * 4 + 3] = fmaf(hv, wb.w, acc[4 + q * 4 + 3]);
    }
  }
#pragma unroll
  for (int off = 32; off > 0; off >>= 1) {
#pragma unroll
    for (int i = 0; i < 20; i++) acc[i] += __shfl_down(acc[i], off);
  }
  __shared__ float red[4][20];
  int wid = t >> 6, lane = t & 63;
  if (lane == 0) {
#pragma unroll
    for (int i = 0; i < 20; i++) red[wid][i] = acc[i];
  }
  __syncthreads();
  if (t == 0) {
    float f[20];
#pragma unroll
    for (int i = 0; i < 20; i++) f[i] = red[0][i] + red[1][i] + red[2][i] + red[3][i];
    float l0 = f[0] + b_cls[0];
    float l1 = f[1] + b_cls[1];
    float l2 = f[2] + b_cls[2];
    float l3 = f[3] + b_cls[3];
    float m = fmaxf(fmaxf(l0, l1), fmaxf(l2, l3));
    float e0 = expf(l0 - m), e1 = expf(l1 - m), e2 = expf(l2 - m), e3 = expf(l3 - m);
    float s = ((e0 + e1) + e2) + e3;
    float vf = valid[r] ? 1.0f : 0.0f;
    scores3[r * 3 + 0] = (e1 / s) * vf;
    scores3[r * 3 + 1] = (e2 / s) * vf;
    scores3[r * 3 + 2] = (e3 / s) * vf;
#pragma unroll
    for (int i = 0; i < 16; i++) bbox16[r * 16 + i] = f[4 + i] + b_bbox[i];
  }
}

// RCNN decode: boxes/keys/scores by ORIGINAL index + Npos. (rank moved to
// k_rc_rank2 so it can run one-wave-per-CU.)
__global__ void __launch_bounds__(1024) k_rc_decode(
    const float* __restrict__ rois,
    const float* __restrict__ scores3,
    const float* __restrict__ bbox16,
    float* __restrict__ dbx, float* __restrict__ dby,
    float* __restrict__ dbX, float* __restrict__ dbY,
    float* __restrict__ dsc, uint64_t* __restrict__ rckeys,
    uint32_t* __restrict__ rc_meta)
{
  __shared__ int s_npos;
  int t = threadIdx.x;
  if (t == 0) s_npos = 0;
  uint64_t k = 0;
  if (t < RC_N) {
    int r = t / 3;
    int c = t - r * 3;
    float ax1 = rois[r * 4 + 0], ay1 = rois[r * 4 + 1];
    float ax2 = rois[r * 4 + 2], ay2 = rois[r * 4 + 3];
    int cb = (c + 1) * 4;
    float dx = bbox16[r * 16 + cb + 0];
    float dy = bbox16[r * 16 + cb + 1];
    float dw = bbox16[r * 16 + cb + 2];
    float dh = bbox16[r * 16 + cb + 3];
    float x1, y1, x2, y2;
    decode_one(ax1, ay1, ax2, ay2, dx, dy, dw, dh, x1, y1, x2, y2);
    float sc = scores3[t];
    dbx[t] = x1; dby[t] = y1; dbX[t] = x2; dbY[t] = y2; dsc[t] = sc;
    if (sc > 0.3f)
      k = ((uint64_t)__float_as_uint(sc) << 32) | (uint32_t)(~(uint32_t)t);
  }
  rckeys[t] = k;   // all 1024 slots (zero-padded tail)
  if (k != 0) atomicAdd(&s_npos, 1);
  __syncthreads();
  if (t == 0) rc_meta[0] = (uint32_t)s_npos;
}

// Rank+scatter, one wave per CU (15 blocks x 64).
__global__ void __launch_bounds__(64) k_rc_rank2(
    const uint64_t* __restrict__ rckeys,
    const float* __restrict__ dbx, const float* __restrict__ dby,
    const float* __restrict__ dbX, const float* __restrict__ dbY,
    const float* __restrict__ dsc,
    float* __restrict__ sx1, float* __restrict__ sy1,
    float* __restrict__ sx2, float* __restrict__ sy2,
    float* __restrict__ ssc, int* __restrict__ sidx)
{
  __shared__ uint64_t keys[1024];
  int lane = threadIdx.x;
  for (int s = lane; s < 1024; s += 64) keys[s] = rckeys[s];
  __syncthreads();
  int e = blockIdx.x * 64 + lane;   // < 960
  uint64_t my = keys[e];
  if (my == 0) return;
  int r = 0;
  for (int j = 0; j < 1024; j += 4) {
    uint64_t k0 = keys[j + 0];
    uint64_t k1 = keys[j + 1];
    uint64_t k2 = keys[j + 2];
    uint64_t k3 = keys[j + 3];
    r += (k0 > my) ? 1 : 0;
    r += (k1 > my) ? 1 : 0;
    r += (k2 > my) ? 1 : 0;
    r += (k3 > my) ? 1 : 0;
  }
  sx1[r] = dbx[e]; sy1[r] = dby[e]; sx2[r] = dbX[e]; sy2[r] = dbY[e];
  ssc[r] = dsc[e]; sidx[r] = e;
}

// 900x15-word IoU>0.5 bitmask in sorted index space (upper triangle only) + diag.
__global__ void __launch_bounds__(256) k_rc_mask(
    const float* __restrict__ sx1, const float* __restrict__ sy1,
    const float* __restrict__ sx2, const float* __restrict__ sy2,
    uint64_t* __restrict__ rcmask, uint64_t* __restrict__ rcdiag)
{
  __shared__ float s1[RC_N], s2[RC_N], s3[RC_N], s4[RC_N];  // 14.4 KB
  int t = threadIdx.x;
  for (int e = t; e < RC_N; e += 256) {
    s1[e] = sx1[e]; s2[e] = sy1[e]; s3[e] = sx2[e]; s4[e] = sy2[e];
  }
  __syncthreads();
  int task = blockIdx.x * 256 + t;
  if (task >= RC_N * RNW) return;
  int row = task / RNW;
  int w   = task - row * RNW;
  if ((w + 1) * 64 <= row) {
    rcmask[(size_t)row * RNW + w] = 0;
    return;
  }
  float ax1 = s1[row], ay1 = s2[row], ax2 = s3[row], ay2 = s4[row];
  float areaA;
  {
#pragma clang fp contract(off)
    areaA = fmaxf((ax2 - ax1) + 1.0f, 0.0f) * fmaxf((ay2 - ay1) + 1.0f, 0.0f);
  }
  int j0 = w << 6;
  uint64_t bits = 0;
  for (int off = 0; off < 64; off++) {
    int jj = (off + t) & 63;
    int j = j0 + jj;
    if (j < RC_N) {
      float iou = iou_ref(ax1, ay1, ax2, ay2, areaA, s1[j], s2[j], s3[j], s4[j]);
      if (iou > 0.5f) bits |= 1ull << jj;
    }
  }
  rcmask[(size_t)row * RNW + w] = bits;
  if (w == (row >> 6)) rcdiag[row] = bits;
}

// ctz-enumeration scan v2 (single wave, diag-shfl + batched L2 row folds).
__global__ void __launch_bounds__(64) k_rc_scan(
    const float* __restrict__ sx1, const float* __restrict__ sy1,
    const float* __restrict__ sx2, const float* __restrict__ sy2,
    const float* __restrict__ ssc, const int* __restrict__ sidx,
    const uint32_t* __restrict__ rc_meta,
    const uint64_t* __restrict__ rcmask,
    const uint64_t* __restrict__ rcdiag,
    float* __restrict__ out)
{
  __shared__ uint64_t sdiag[RC_N];            // 7.2 KB
  __shared__ int keepPos[FIN_N];
  int lane = threadIdx.x;
  for (int e = lane; e < RC_N; e += 64) sdiag[e] = rcdiag[e];
  __syncthreads();
  int Npos = (int)min(rc_meta[0], (uint32_t)RC_N);
  uint64_t sup = 0;
  int nk = 0;
  int nwords = (Npos + 63) >> 6;
  for (int w = 0; w < nwords && nk < FIN_N; w++) {
    uint64_t cw = (uint64_t)__shfl((unsigned long long)sup, w);
    int ci = (w << 6) + lane;
    uint64_t dg = (ci < Npos) ? sdiag[ci] : 0;
    int lim = Npos - (w << 6);
    uint64_t range = (lim >= 64) ? ~0ull : ((1ull << lim) - 1ull);
    uint64_t rem = (~cw) & range;
    uint64_t keepbits = 0;
    while (rem && nk < FIN_N) {
      int b = __builtin_ctzll(rem);
      keepbits |= 1ull << b;
      if (lane == 0) keepPos[nk] = (w << 6) + b;
      nk++;
      uint64_t roww = (uint64_t)__shfl((unsigned long long)dg, b);
      rem &= ~(roww | (1ull << b));
    }
    while (keepbits) {
      uint64_t r0 = 0, r1 = 0, r2 = 0, r3 = 0, r4 = 0, r5 = 0, r6 = 0, r7 = 0;
      int b;
      if (keepbits) { b = __builtin_ctzll(keepbits); keepbits &= keepbits - 1;
        if (lane < RNW) r0 = rcmask[(size_t)((w << 6) + b) * RNW + lane]; }
      if (keepbits) { b = __builtin_ctzll(keepbits); keepbits &= keepbits - 1;
        if (lane < RNW) r1 = rcmask[(size_t)((w << 6) + b) * RNW + lane]; }
      if (keepbits) { b = __builtin_ctzll(keepbits); keepbits &= keepbits - 1;
        if (lane < RNW) r2 = rcmask[(size_t)((w << 6) + b) * RNW + lane]; }
      if (keepbits) { b = __builtin_ctzll(keepbits); keepbits &= keepbits - 1;
        if (lane < RNW) r3 = rcmask[(size_t)((w << 6) + b) * RNW + lane]; }
      if (keepbits) { b = __builtin_ctzll(keepbits); keepbits &= keepbits - 1;
        if (lane < RNW) r4 = rcmask[(size_t)((w << 6) + b) * RNW + lane]; }
      if (keepbits) { b = __builtin_ctzll(keepbits); keepbits &= keepbits - 1;
        if (lane < RNW) r5 = rcmask[(size_t)((w << 6) + b) * RNW + lane]; }
      if (keepbits) { b = __builtin_ctzll(keepbits); keepbits &= keepbits - 1;
        if (lane < RNW) r6 = rcmask[(size_t)((w << 6) + b) * RNW + lane]; }
      if (keepbits) { b = __builtin_ctzll(keepbits); keepbits &= keepbits - 1;
        if (lane < RNW) r7 = rcmask[(size_t)((w << 6) + b) * RNW + lane]; }
      sup |= ((r0 | r1) | (r2 | r3)) | ((r4 | r5) | (r6 | r7));
    }
  }
  __syncthreads();
  for (int k = lane; k < nk; k += 64) {
    int i = keepPos[k];
    int m = sidx[i];
    out[k * 6 + 0] = sx1[i];
    out[k * 6 + 1] = sy1[i];
    out[k * 6 + 2] = sx2[i];
    out[k * 6 + 3] = sy2[i];
    out[k * 6 + 4] = ssc[i];
    out[k * 6 + 5] = (float)(m - (m / 3) * 3 + 1);
  }
  for (int e = nk * 6 + lane; e < FIN_N * 6; e += 64) out[e] = 0.0f;
}

extern "C" void kernel_launch(void* const* d_in, const int* in_sizes, int n_in,
                              void* d_out, int out_size, void* d_ws, size_t ws_size,
                              hipStream_t stream)
{
  (void)in_sizes; (void)n_in; (void)out_size; (void)ws_size;
  const float* rpn_cls  = (const float*)d_in[0];
  const float* rpn_bbox = (const float*)d_in[1];
  const float* ft       = (const float*)d_in[2];
  const float* w1       = (const float*)d_in[3];
  const float* b1       = (const float*)d_in[4];
  const float* w_cls    = (const float*)d_in[5];
  const float* b_cls    = (const float*)d_in[6];
  const float* w_bbox   = (const float*)d_in[7];
  const float* b_bbox   = (const float*)d_in[8];
  float* out = (float*)d_out;

  char* ws = (char*)d_ws;
  size_t off = 0;
  auto alloc = [&](size_t bytes) -> void* {
    void* p = (void*)(ws + off);
    off += (bytes + 15) & ~(size_t)15;
    return p;
  };
  uint32_t* hist1  = (uint32_t*)alloc(65536 * 4);
  uint32_t* hist2  = (uint32_t*)alloc(65536 * 4);
  uint32_t* meta   = (uint32_t*)alloc(32 * 4);        // contiguous with hists
  float*    scores = (float*)alloc((size_t)NTOT * 4);
  uint64_t* gt     = (uint64_t*)alloc(3008 * 8);
  uint64_t* tie    = (uint64_t*)alloc(TIE_CAP * 8);
  float*    bxx1 = (float*)alloc(PRE_N * 4);
  float*    bxy1 = (float*)alloc(PRE_N * 4);
  float*    bxx2 = (float*)alloc(PRE_N * 4);
  float*    bxy2 = (float*)alloc(PRE_N * 4);
  float*    rois  = (float*)alloc(KEEP_N * 4 * 4);
  uint32_t* valid = (uint32_t*)alloc(KEEP_N * 4);
  float*    feats = (float*)alloc((size_t)KEEP_N * FEAT_N * 4);
  float*    hbuf  = (float*)alloc((size_t)KEEP_N * HID_N * 4);
  float*    scores3 = (float*)alloc(RC_N * 4);
  float*    bbox16  = (float*)alloc(KEEP_N * 16 * 4);
  float*    sx1 = (float*)alloc(RC_N * 4);
  float*    sy1 = (float*)alloc(RC_N * 4);
  float*    sx2 = (float*)alloc(RC_N * 4);
  float*    sy2 = (float*)alloc(RC_N * 4);
  float*    ssc = (float*)alloc(RC_N * 4);
  int*      sidx = (int*)alloc(RC_N * 4);
  uint32_t* rc_meta = (uint32_t*)alloc(16 * 4);
  float*    dbx = (float*)alloc(RC_N * 4);
  float*    dby = (float*)alloc(RC_N * 4);
  float*    dbX = (float*)alloc(RC_N * 4);
  float*    dbY = (float*)alloc(RC_N * 4);
  float*    dsc = (float*)alloc(RC_N * 4);
  uint64_t* rckeys = (uint64_t*)alloc(1024 * 8);
  uint64_t* rowmask = (uint64_t*)alloc((size_t)3008 * NW * 8);
  uint64_t* diag    = (uint64_t*)alloc(3008 * 8);
  uint64_t* rcmask  = (uint64_t*)alloc((size_t)RC_N * RNW * 8);
  uint64_t* rcdiag  = (uint64_t*)alloc(904 * 8);

  k_decode_score<<<NTOT / 256, 256, 0, stream>>>(rpn_cls, rpn_bbox, scores, hist1);
  k_hist_hi<<<NTOT / 256, 256, 0, stream>>>(scores, hist1);
  k_findbin1<<<1, 1024, 0, stream>>>(hist1, meta);
  k_hist_lo<<<NTOT / 256, 256, 0, stream>>>(scores, meta, hist2);
  k_findT<<<1, 1024, 0, stream>>>(hist2, meta);
  k_compact<<<NTOT / 256, 256, 0, stream>>>(scores, meta, gt, tie, meta + 8);
  k_rank_gather<<<63, 64, 0, stream>>>(gt, tie, meta + 8, rpn_bbox,
                                       bxx1, bxy1, bxx2, bxy2);
  k_iou_mask<<<(PRE_N * NW + 255) / 256, 256, 0, stream>>>(bxx1, bxy1, bxx2, bxy2,
                                                           rowmask, diag);
  k_rpn_scan<<<1, 64, 0, stream>>>(bxx1, bxy1, bxx2, bxy2, meta + 8,
                                   rowmask, diag, rois, valid);
  k_psroi<<<KEEP_N, 512, 0, stream>>>(ft, rois, valid, feats);
  k_fc1<<<dim3(HID_N / 256, KEEP_N / FC1_MT), 256, 0, stream>>>(feats, w1, b1, hbuf);
  k_fc2<<<KEEP_N, 256, 0, stream>>>(hbuf, w_cls, b_cls, w_bbox, b_bbox, valid,
                                    scores3, bbox16);
  k_rc_decode<<<1, 1024, 0, stream>>>(rois, scores3, bbox16,
                                      dbx, dby, dbX, dbY, dsc, rckeys, rc_meta);
  k_rc_rank2<<<15, 64, 0, stream>>>(rckeys, dbx, dby, dbX, dbY, dsc,
                                    sx1, sy1, sx2, sy2, ssc, sidx);
  k_rc_mask<<<(RC_N * RNW + 255) / 256, 256, 0, stream>>>(sx1, sy1, sx2, sy2,
                                                          rcmask, rcdiag);
  k_rc_scan<<<1, 64, 0, stream>>>(sx1, sy1, sx2, sy2, ssc, sidx, rc_meta,
                                  rcmask, rcdiag, out);
}